// Round 2
// baseline (73154.462 us; speedup 1.0000x reference)
//
#include <hip/hip_runtime.h>
#include <hip/hip_cooperative_groups.h>
#include <cmath>

namespace cg = cooperative_groups;

// Problem constants (reference: B,T,D,H,O = 32,2048,256,512,256)
#define NB 32
#define NT 2048
#define ND 256
#define NH 512
#define NO 256
#define NK 768            // D + H fused K dimension
#define NWG 256           // one workgroup per CU
#define NTHR 256
#define JPW 2             // h-columns owned per WG (256*2 = 512)
#define CPW 8             // z-columns per WG = 4 gates * JPW
#define WST 772           // padded K stride (772 % 32 == 4 -> bank spread; %4==0 -> b128 aligned)

__device__ __forceinline__ float sigmoidf_(float x) { return 1.0f / (1.0f + __expf(-x)); }

#define FMA4(a, xv, wv)                     \
    a = fmaf((xv).x, (wv).x, a);            \
    a = fmaf((xv).y, (wv).y, a);            \
    a = fmaf((xv).z, (wv).z, a);            \
    a = fmaf((xv).w, (wv).w, a);

__global__ __launch_bounds__(NTHR) void lstm_fused(
    const float* __restrict__ xin,  // [B, T, D]
    const float* __restrict__ Wx,   // [D, 4H]
    const float* __restrict__ Wh,   // [H, 4H]
    const float* __restrict__ bz,   // [4H]
    const float* __restrict__ Wd,   // [H, O]
    const float* __restrict__ bd,   // [O]
    float* __restrict__ out,        // [B, 1, O]
    float* __restrict__ ws)         // scratch: h double buffer (2 * B*H floats)
{
    __shared__ float sW[CPW][WST];    // weight slice, K-major rows per z-column
    __shared__ float sXH[NB][WST];    // [x_t | h_t] per batch row
    __shared__ float sZp[8][NB][CPW]; // k-split partials
    __shared__ float sZ[NB][CPW];     // reduced gate pre-activations
    __shared__ float sC[NB][JPW];     // cell state for owned columns
    __shared__ float sBias[CPW];
    __shared__ float sRed[8][32];     // dense epilogue reduction

    const int wg  = blockIdx.x;
    const int tid = threadIdx.x;
    const int j0  = wg * JPW;

    float* hb0 = ws;
    float* hb1 = ws + NB * NH;

    // ---- one-time init: stage weight slice, bias, zero c-state and hb0 ----
    for (int idx = tid; idx < CPW * NK; idx += NTHR) {
        int c = idx & 7, k = idx >> 3;
        int col = (c >> 1) * NH + j0 + (c & 1);   // c = gate*2 + jj
        sW[c][k] = (k < ND) ? Wx[k * (4 * NH) + col]
                            : Wh[(k - ND) * (4 * NH) + col];
    }
    if (tid < CPW) sBias[tid] = bz[(tid >> 1) * NH + j0 + (tid & 1)];
    if (tid < NB * JPW) sC[tid >> 1][tid & 1] = 0.0f;
    {
        int g = wg * NTHR + tid;          // first 64 WGs zero hb0
        if (g < NB * NH) hb0[g] = 0.0f;
    }

    cg::grid_group grid = cg::this_grid();
    grid.sync();

    // compute-thread decomposition: k-split 8, 8 b-positions (strided by 8), 4 c-positions
    const int kk    = tid >> 5;        // 0..7  -> K chunk of 96
    const int pos   = tid & 31;
    const int bb    = pos >> 2;        // 0..7  -> b in {bb, bb+8, bb+16, bb+24}
    const int c0    = (pos & 3) << 1;  // 0,2,4,6 -> columns c0, c0+1
    const int kbase = kk * 96;

    for (int t = 0; t < NT; ++t) {
        const float* hcur = (t & 1) ? hb1 : hb0;
        float*       hnxt = (t & 1) ? hb0 : hb1;

        // ---- stage x_t (32x256) and h_t (32x512) into LDS, coalesced f4 ----
        #pragma unroll
        for (int l = 0; l < 8; ++l) {
            int q = tid + l * NTHR;
            int b = q >> 6, k4 = (q & 63) << 2;
            *(float4*)&sXH[b][k4] =
                *(const float4*)(xin + ((size_t)(b * NT + t)) * ND + k4);
        }
        #pragma unroll
        for (int l = 0; l < 16; ++l) {
            int q = tid + l * NTHR;
            int b = q >> 7, k4 = (q & 127) << 2;
            *(float4*)&sXH[b][ND + k4] = *(const float4*)(hcur + b * NH + k4);
        }
        __syncthreads();

        // ---- z-tile: 4b x 2c per thread over K chunk of 96 ----
        float acc[4][2];
        #pragma unroll
        for (int i = 0; i < 4; ++i) { acc[i][0] = 0.f; acc[i][1] = 0.f; }

        #pragma unroll 4
        for (int k4 = 0; k4 < 96; k4 += 4) {
            int k = kbase + k4;
            float4 x0 = *(const float4*)&sXH[bb     ][k];
            float4 x1 = *(const float4*)&sXH[bb +  8][k];
            float4 x2 = *(const float4*)&sXH[bb + 16][k];
            float4 x3 = *(const float4*)&sXH[bb + 24][k];
            float4 w0 = *(const float4*)&sW[c0    ][k];
            float4 w1 = *(const float4*)&sW[c0 + 1][k];
            FMA4(acc[0][0], x0, w0)  FMA4(acc[0][1], x0, w1)
            FMA4(acc[1][0], x1, w0)  FMA4(acc[1][1], x1, w1)
            FMA4(acc[2][0], x2, w0)  FMA4(acc[2][1], x2, w1)
            FMA4(acc[3][0], x3, w0)  FMA4(acc[3][1], x3, w1)
        }
        #pragma unroll
        for (int i = 0; i < 4; ++i) {
            sZp[kk][bb + 8 * i][c0]     = acc[i][0];
            sZp[kk][bb + 8 * i][c0 + 1] = acc[i][1];
        }
        __syncthreads();

        // ---- reduce k-split partials: one (b,c) per thread ----
        {
            int b = tid >> 3, c = tid & 7;
            float z = sBias[c];
            #pragma unroll
            for (int k2 = 0; k2 < 8; ++k2) z += sZp[k2][b][c];
            sZ[b][c] = z;
        }
        __syncthreads();

        // ---- gates + cell update for owned columns; publish h_new ----
        if (tid < NB * JPW) {
            int b = tid >> 1, jj = tid & 1;
            float zi = sZ[b][0 + jj];
            float zf = sZ[b][2 + jj];
            float zg = sZ[b][4 + jj];
            float zo = sZ[b][6 + jj];
            float cp = sC[b][jj];
            float cn = sigmoidf_(zf) * cp + sigmoidf_(zi) * tanhf(zg);
            sC[b][jj] = cn;
            hnxt[b * NH + j0 + jj] = sigmoidf_(zo) * tanhf(cn);
        }
        grid.sync();
    }

    // ---- dense epilogue: out[b, o] = h_last @ Wd + bd ----
    // final h lives in hb0 (t=2047 wrote hnxt = hb0); already fenced by grid.sync
    {
        int b  = wg >> 3;
        int ob = (wg & 7) * 32;
        int kd = tid >> 5, oo = tid & 31;
        const float* hrow = hb0 + b * NH;
        float p = 0.f;
        for (int k = kd * 64; k < kd * 64 + 64; ++k)
            p = fmaf(hrow[k], Wd[k * NO + ob + oo], p);
        sRed[kd][oo] = p;
        __syncthreads();
        if (tid < 32) {
            float s = bd[ob + tid];
            #pragma unroll
            for (int k2 = 0; k2 < 8; ++k2) s += sRed[k2][tid];
            out[b * NO + ob + tid] = s;
        }
    }
}

extern "C" void kernel_launch(void* const* d_in, const int* in_sizes, int n_in,
                              void* d_out, int out_size, void* d_ws, size_t ws_size,
                              hipStream_t stream) {
    const float* xin = (const float*)d_in[0];
    const float* Wx  = (const float*)d_in[1];
    const float* Wh  = (const float*)d_in[2];
    const float* bz  = (const float*)d_in[3];
    const float* Wd  = (const float*)d_in[4];
    const float* bd  = (const float*)d_in[5];
    float* out = (float*)d_out;
    float* ws  = (float*)d_ws;

    void* args[] = { &xin, &Wx, &Wh, &bz, &Wd, &bd, &out, &ws };
    hipLaunchCooperativeKernel((const void*)lstm_fused, dim3(NWG), dim3(NTHR),
                               args, 0, stream);
}

// Round 3
// 10893.426 us; speedup vs baseline: 6.7155x; 6.7155x over previous
//
#include <hip/hip_runtime.h>
#include <hip/hip_cooperative_groups.h>
#include <cmath>

namespace cg = cooperative_groups;

// Problem constants (reference: B,T,D,H,O = 32,2048,256,512,256)
#define NB 32
#define NT 2048
#define ND 256
#define NH 512
#define NO 256
#define NK 768
#define NWG 256           // one workgroup per CU
#define NTHR 256
#define JPW 2             // h-columns owned per WG
#define CPW 8             // z-columns per WG = 4 gates * JPW
#define WST 772           // padded K stride (%32==4 bank spread, %4==0 for b128)
#define NLEAF 16          // barrier tree leaves

__device__ __forceinline__ float sigmoidf_(float x) { return 1.0f / (1.0f + __expf(-x)); }

// Coherent (MALL-level) load/store: sc0 sc1 bypass L1+L2 so cross-XCD
// visibility needs NO buffer_wbl2 / buffer_inv (the grid.sync killer).
__device__ __forceinline__ float4 gload4_coh(const float* p) {
    float4 r;
    asm volatile("global_load_dwordx4 %0, %1, off sc0 sc1" : "=v"(r) : "v"(p));
    return r;
}
__device__ __forceinline__ void gstore_coh(float* p, float v) {
    asm volatile("global_store_dword %0, %1, off sc0 sc1" :: "v"(p), "v"(v) : "memory");
}

#define FMA4(a, xv, wv)                     \
    a = fmaf((xv).x, (wv).x, a);            \
    a = fmaf((xv).y, (wv).y, a);            \
    a = fmaf((xv).z, (wv).z, a);            \
    a = fmaf((xv).w, (wv).w, a);

__global__ __launch_bounds__(NTHR) void lstm_fused(
    const float* __restrict__ xin,  // [B, T, D]
    const float* __restrict__ Wx,   // [D, 4H]
    const float* __restrict__ Wh,   // [H, 4H]
    const float* __restrict__ bz,   // [4H]
    const float* __restrict__ Wd,   // [H, O]
    const float* __restrict__ bd,   // [O]
    float* __restrict__ out,        // [B, 1, O]
    float* __restrict__ ws)         // h dbuf (2*B*H f32) + barrier words
{
    __shared__ float sW[CPW][WST];
    __shared__ float sXH[NB][WST];    // cols [0,256)=x_t, [256,768)=h_t
    __shared__ float sZp[8][NB][CPW];
    __shared__ float sZ[NB][CPW];
    __shared__ float sC[NB][JPW];
    __shared__ float sBias[CPW];
    __shared__ float sRed[8][32];

    const int wg  = blockIdx.x;
    const int tid = threadIdx.x;
    const int j0  = wg * JPW;

    float* hb0 = ws;
    float* hb1 = ws + NB * NH;
    unsigned* barw  = (unsigned*)(ws + 2 * NB * NH); // leaf i at barw[i*32] (128B apart)
    unsigned* rootp = barw + NLEAF * 32;

    // ---- one-time init ----
    for (int idx = tid; idx < CPW * NK; idx += NTHR) {
        int c = idx & 7, k = idx >> 3;
        int col = (c >> 1) * NH + j0 + (c & 1);
        sW[c][k] = (k < ND) ? Wx[k * (4 * NH) + col]
                            : Wh[(k - ND) * (4 * NH) + col];
    }
    if (tid < CPW) sBias[tid] = bz[(tid >> 1) * NH + j0 + (tid & 1)];
    if (tid < NB * JPW) sC[tid >> 1][tid & 1] = 0.0f;
    { int g = wg * NTHR + tid; if (g < NB * NH) hb0[g] = 0.0f; }
    if (wg == 0 && tid <= NLEAF) barw[tid * 32] = 0u;  // 16 leaves + root

    cg::grid_group grid = cg::this_grid();
    grid.sync();   // once: flushes init stores to the coherent point

    // compute decomposition: kk = K-split 8, 8 b-positions (stride 8), 4 col-pairs
    const int kk = tid >> 5, pos = tid & 31;
    const int bb = pos >> 2, c0 = (pos & 3) << 1;

    float acc[4][2];

    // ---- prologue: stage x_0, phase-X accumulate (h-independent) ----
    #pragma unroll
    for (int l = 0; l < 8; ++l) {
        int q = tid + l * NTHR;
        int b = q >> 6, k4 = (q & 63) << 2;
        *(float4*)&sXH[b][k4] = *(const float4*)(xin + ((size_t)b * NT + 0) * ND + k4);
    }
    __syncthreads();
    #pragma unroll
    for (int i = 0; i < 4; ++i) { acc[i][0] = 0.f; acc[i][1] = 0.f; }
    #pragma unroll
    for (int k4 = 0; k4 < 32; k4 += 4) {
        const int k = (kk << 5) + k4;
        float4 x0 = *(const float4*)&sXH[bb     ][k];
        float4 x1 = *(const float4*)&sXH[bb +  8][k];
        float4 x2 = *(const float4*)&sXH[bb + 16][k];
        float4 x3 = *(const float4*)&sXH[bb + 24][k];
        float4 w0 = *(const float4*)&sW[c0    ][k];
        float4 w1 = *(const float4*)&sW[c0 + 1][k];
        FMA4(acc[0][0], x0, w0)  FMA4(acc[0][1], x0, w1)
        FMA4(acc[1][0], x1, w0)  FMA4(acc[1][1], x1, w1)
        FMA4(acc[2][0], x2, w0)  FMA4(acc[2][1], x2, w1)
        FMA4(acc[3][0], x3, w0)  FMA4(acc[3][1], x3, w1)
    }

    for (int t = 0; t < NT; ++t) {
        const float* hcur = (t & 1) ? hb1 : hb0;
        float*       hnxt = (t & 1) ? hb0 : hb1;

        // ---- A: wait for epoch t (all h_t slices at the MALL) ----
        if (tid == 0) {
            const unsigned tgt = (unsigned)NLEAF * (unsigned)t;
            while (__hip_atomic_load(rootp, __ATOMIC_RELAXED,
                                     __HIP_MEMORY_SCOPE_AGENT) < tgt) {}
        }
        __syncthreads();

        // ---- B: coherent h_t stage -> LDS ----
        {
            float4 hv[16];
            #pragma unroll
            for (int l = 0; l < 16; ++l) {
                int q = tid + l * NTHR;
                int b = q >> 7, k4 = (q & 127) << 2;
                hv[l] = gload4_coh(hcur + b * NH + k4);
            }
            asm volatile("s_waitcnt vmcnt(0)" ::: "memory");
            __builtin_amdgcn_sched_barrier(0);
            #pragma unroll
            for (int l = 0; l < 16; ++l) {
                int q = tid + l * NTHR;
                int b = q >> 7, k4 = (q & 127) << 2;
                *(float4*)&sXH[b][ND + k4] = hv[l];
            }
        }
        __syncthreads();

        // ---- C: phase-H accumulate (K=512) on top of phase-X partials ----
        #pragma unroll 4
        for (int k4 = 0; k4 < 64; k4 += 4) {
            const int k = ND + (kk << 6) + k4;
            float4 x0 = *(const float4*)&sXH[bb     ][k];
            float4 x1 = *(const float4*)&sXH[bb +  8][k];
            float4 x2 = *(const float4*)&sXH[bb + 16][k];
            float4 x3 = *(const float4*)&sXH[bb + 24][k];
            float4 w0 = *(const float4*)&sW[c0    ][k];
            float4 w1 = *(const float4*)&sW[c0 + 1][k];
            FMA4(acc[0][0], x0, w0)  FMA4(acc[0][1], x0, w1)
            FMA4(acc[1][0], x1, w0)  FMA4(acc[1][1], x1, w1)
            FMA4(acc[2][0], x2, w0)  FMA4(acc[2][1], x2, w1)
            FMA4(acc[3][0], x3, w0)  FMA4(acc[3][1], x3, w1)
        }

        // ---- D: k-split partials -> reduce ----
        #pragma unroll
        for (int i = 0; i < 4; ++i) {
            sZp[kk][bb + 8 * i][c0]     = acc[i][0];
            sZp[kk][bb + 8 * i][c0 + 1] = acc[i][1];
        }
        __syncthreads();
        {
            int b = tid >> 3, c = tid & 7;
            float z = sBias[c];
            #pragma unroll
            for (int k2 = 0; k2 < 8; ++k2) z += sZp[k2][b][c];
            sZ[b][c] = z;
        }
        __syncthreads();

        // ---- E: gates + coherent h_{t+1} publish ----
        if (tid < NB * JPW) {
            int b = tid >> 1, jj = tid & 1;
            float zi = sZ[b][0 + jj];
            float zf = sZ[b][2 + jj];
            float zg = sZ[b][4 + jj];
            float zo = sZ[b][6 + jj];
            float cp = sC[b][jj];
            float cn = sigmoidf_(zf) * cp + sigmoidf_(zi) * tanhf(zg);
            sC[b][jj] = cn;
            gstore_coh(&hnxt[b * NH + j0 + jj], sigmoidf_(zo) * tanhf(cn));
        }
        asm volatile("s_waitcnt vmcnt(0)" ::: "memory");  // h at MALL before arrival
        __syncthreads();

        // ---- G: arrive epoch t+1 (tree: leaf -> root), NO wait here ----
        if (tid == 0) {
            unsigned old = __hip_atomic_fetch_add(&barw[(wg & (NLEAF - 1)) * 32], 1u,
                                                  __ATOMIC_RELAXED, __HIP_MEMORY_SCOPE_AGENT);
            if ((old & (NLEAF - 1)) == NLEAF - 1)
                __hip_atomic_fetch_add(rootp, 1u,
                                       __ATOMIC_RELAXED, __HIP_MEMORY_SCOPE_AGENT);
        }

        // ---- H: overlap barrier latency with x_{t+1} stage + phase-X ----
        if (t + 1 < NT) {
            #pragma unroll
            for (int l = 0; l < 8; ++l) {
                int q = tid + l * NTHR;
                int b = q >> 6, k4 = (q & 63) << 2;
                *(float4*)&sXH[b][k4] =
                    *(const float4*)(xin + ((size_t)b * NT + (t + 1)) * ND + k4);
            }
            __syncthreads();
            #pragma unroll
            for (int i = 0; i < 4; ++i) { acc[i][0] = 0.f; acc[i][1] = 0.f; }
            #pragma unroll
            for (int k4 = 0; k4 < 32; k4 += 4) {
                const int k = (kk << 5) + k4;
                float4 x0 = *(const float4*)&sXH[bb     ][k];
                float4 x1 = *(const float4*)&sXH[bb +  8][k];
                float4 x2 = *(const float4*)&sXH[bb + 16][k];
                float4 x3 = *(const float4*)&sXH[bb + 24][k];
                float4 w0 = *(const float4*)&sW[c0    ][k];
                float4 w1 = *(const float4*)&sW[c0 + 1][k];
                FMA4(acc[0][0], x0, w0)  FMA4(acc[0][1], x0, w1)
                FMA4(acc[1][0], x1, w0)  FMA4(acc[1][1], x1, w1)
                FMA4(acc[2][0], x2, w0)  FMA4(acc[2][1], x2, w1)
                FMA4(acc[3][0], x3, w0)  FMA4(acc[3][1], x3, w1)
            }
        }
    }

    // ---- epilogue: wait epoch NT, then out = h_last @ Wd + bd ----
    if (tid == 0) {
        const unsigned tgt = (unsigned)NLEAF * (unsigned)NT;
        while (__hip_atomic_load(rootp, __ATOMIC_RELAXED,
                                 __HIP_MEMORY_SCOPE_AGENT) < tgt) {}
    }
    __syncthreads();
    {
        int b  = wg >> 3;               // final h in hb0 ((NT-1)&1=1 -> hnxt=hb0)
        int ob = (wg & 7) * 32;
        float* sRow = &sXH[0][0];
        if (tid < 128) {
            float4 v = gload4_coh(hb0 + b * NH + (tid << 2));
            asm volatile("s_waitcnt vmcnt(0)" ::: "memory");
            __builtin_amdgcn_sched_barrier(0);
            *(float4*)&sRow[tid << 2] = v;
        }
        __syncthreads();
        int kd = tid >> 5, oo = tid & 31;
        float p = 0.f;
        for (int k = kd * 64; k < kd * 64 + 64; ++k)
            p = fmaf(sRow[k], Wd[k * NO + ob + oo], p);
        sRed[kd][oo] = p;
        __syncthreads();
        if (tid < 32) {
            float s = bd[ob + tid];
            #pragma unroll
            for (int k2 = 0; k2 < 8; ++k2) s += sRed[k2][tid];
            out[b * NO + ob + tid] = s;
        }
    }
}

extern "C" void kernel_launch(void* const* d_in, const int* in_sizes, int n_in,
                              void* d_out, int out_size, void* d_ws, size_t ws_size,
                              hipStream_t stream) {
    const float* xin = (const float*)d_in[0];
    const float* Wx  = (const float*)d_in[1];
    const float* Wh  = (const float*)d_in[2];
    const float* bz  = (const float*)d_in[3];
    const float* Wd  = (const float*)d_in[4];
    const float* bd  = (const float*)d_in[5];
    float* out = (float*)d_out;
    float* ws  = (float*)d_ws;

    void* args[] = { &xin, &Wx, &Wh, &bz, &Wd, &bd, &out, &ws };
    hipLaunchCooperativeKernel((const void*)lstm_fused, dim3(NWG), dim3(NTHR),
                               args, 0, stream);
}

// Round 4
// 8142.664 us; speedup vs baseline: 8.9841x; 1.3378x over previous
//
#include <hip/hip_runtime.h>
#include <hip/hip_cooperative_groups.h>
#include <hip/hip_fp16.h>
#include <cmath>

namespace cg = cooperative_groups;

// Problem constants (reference: B,T,D,H,O = 32,2048,256,512,256)
#define NB 32
#define NT 2048
#define ND 256
#define NH 512
#define NO 256
#define NK 768
#define NWG 256           // 4 groups x 64 WGs; one WG per CU
#define NTHR 256
#define NGRP 4
#define GWG 64            // WGs per group
#define GB 8              // batch rows per group
#define JPW 8             // h-columns owned per WG (64*8 = 512)
#define CPW 32            // z-columns per WG = 4 gates * JPW
#define XST 772           // sXH row stride (%32==4 bank spread, %4==0 for b128)
#define WPAD 36           // sWt row stride (32 cols + 4 pad, b128-aligned)

__device__ __forceinline__ float sigmoidf_(float x) { return 1.0f / (1.0f + __expf(-x)); }

// Coherent (MALL-level) ops: sc0 sc1 bypass L1/L2 -> cross-XCD visible
// without any cache flush/invalidate.
__device__ __forceinline__ unsigned gloadu_coh(const unsigned* p) {
    unsigned r;
    asm volatile("global_load_dword %0, %1, off sc0 sc1\n\ts_waitcnt vmcnt(0)"
                 : "=v"(r) : "v"(p) : "memory");
    return r;
}
__device__ __forceinline__ uint4 gload4u_coh(const unsigned* p) {
    uint4 r;
    asm volatile("global_load_dwordx4 %0, %1, off sc0 sc1" : "=v"(r) : "v"(p));
    return r;
}
__device__ __forceinline__ void gstoreu_coh(unsigned* p, unsigned v) {
    asm volatile("global_store_dword %0, %1, off sc0 sc1" :: "v"(p), "v"(v) : "memory");
}

#define ACCROW(i, xv)                                              \
    acc[i][0] = fmaf((xv).x, w0.x, acc[i][0]);                     \
    acc[i][0] = fmaf((xv).y, w1.x, acc[i][0]);                     \
    acc[i][0] = fmaf((xv).z, w2.x, acc[i][0]);                     \
    acc[i][0] = fmaf((xv).w, w3.x, acc[i][0]);                     \
    acc[i][1] = fmaf((xv).x, w0.y, acc[i][1]);                     \
    acc[i][1] = fmaf((xv).y, w1.y, acc[i][1]);                     \
    acc[i][1] = fmaf((xv).z, w2.y, acc[i][1]);                     \
    acc[i][1] = fmaf((xv).w, w3.y, acc[i][1]);                     \
    acc[i][2] = fmaf((xv).x, w0.z, acc[i][2]);                     \
    acc[i][2] = fmaf((xv).y, w1.z, acc[i][2]);                     \
    acc[i][2] = fmaf((xv).z, w2.z, acc[i][2]);                     \
    acc[i][2] = fmaf((xv).w, w3.z, acc[i][2]);                     \
    acc[i][3] = fmaf((xv).x, w0.w, acc[i][3]);                     \
    acc[i][3] = fmaf((xv).y, w1.w, acc[i][3]);                     \
    acc[i][3] = fmaf((xv).z, w2.w, acc[i][3]);                     \
    acc[i][3] = fmaf((xv).w, w3.w, acc[i][3]);

#define STEP4(kb) {                                                \
    const int k_ = (kb);                                           \
    float4 xa = *(const float4*)&sXH[b0    ][k_];                  \
    float4 xb = *(const float4*)&sXH[b0 + 2][k_];                  \
    float4 xc = *(const float4*)&sXH[b0 + 4][k_];                  \
    float4 xd = *(const float4*)&sXH[b0 + 6][k_];                  \
    float4 w0 = *(const float4*)&sWt[k_    ][c0];                  \
    float4 w1 = *(const float4*)&sWt[k_ + 1][c0];                  \
    float4 w2 = *(const float4*)&sWt[k_ + 2][c0];                  \
    float4 w3 = *(const float4*)&sWt[k_ + 3][c0];                  \
    ACCROW(0, xa) ACCROW(1, xb) ACCROW(2, xc) ACCROW(3, xd) }

__global__ __launch_bounds__(NTHR) void lstm_fused(
    const float* __restrict__ xin,  // [B, T, D]
    const float* __restrict__ Wx,   // [D, 4H]
    const float* __restrict__ Wh,   // [H, 4H]
    const float* __restrict__ bz,   // [4H]
    const float* __restrict__ Wd,   // [H, O]
    const float* __restrict__ bd,   // [O]
    float* __restrict__ out,        // [B, 1, O]
    float* __restrict__ ws)         // fp16 h dbuf per group + flags
{
    __shared__ float sWt[NK][WPAD];   // transposed W slice: [k][c], c=gate*8+jj
    __shared__ float sXH[GB][XST];    // [0,256)=x_t, [256,768)=h_t (fp32)
    __shared__ float sZp[16][GB][CPW];// k-split partials (aliased by epilogue)
    __shared__ float sZ[GB][CPW];
    __shared__ float sC[GB][JPW];
    __shared__ float sBias[CPW];
    __shared__ float sRed[8][32];

    const int wg  = blockIdx.x;
    const int tid = threadIdx.x;
    const int g   = wg >> 6;          // group 0..3
    const int wgl = wg & 63;          // index in group
    const int j0  = wgl * JPW;        // h-col base
    const int g8  = g * GB;           // global batch row base

    // ws layout (u32): h buffers [4 groups][2 bufs][2048 u32], then flags
    unsigned* hws   = (unsigned*)ws;
    unsigned* flags = hws + NGRP * 2 * (GB * NH / 2);  // [4][64] stride 32

    // ---- one-time init: transposed W slice, bias, zero c/h0/flag ----
    for (int it = 0; it < 24; ++it) {
        int idx  = it * NTHR + tid;        // 0..6143 = 768k * 4gate * 2half
        int half = idx & 1;
        int gate = (idx >> 1) & 3;
        int k    = idx >> 3;
        const float* src = (k < ND ? Wx + (size_t)k * (4 * NH)
                                   : Wh + (size_t)(k - ND) * (4 * NH))
                           + gate * NH + j0 + half * 4;
        *(float4*)&sWt[k][gate * 8 + half * 4] = *(const float4*)src;
    }
    if (tid < CPW) sBias[tid] = bz[(tid >> 3) * NH + j0 + (tid & 7)];
    if (tid < GB * JPW) sC[tid >> 3][tid & 7] = 0.0f;
    {
        int gid = wg * NTHR + tid;         // zero h buf0 of every group
        if (gid < NGRP * 2048) {
            int gg = gid >> 11, idx = gid & 2047;
            gstoreu_coh(&hws[gg * 4096 + idx], 0u);
        }
    }
    if (tid == 0) gstoreu_coh(&flags[(g * GWG + wgl) * 32], 0u);

    cg::grid_group grid = cg::this_grid();
    grid.sync();   // makes zeroed h/flags coherently visible everywhere

    // compute decomposition: kk = tid>>4 (16 K-slices), 16 positions = 2b x 8c
    const int kk = tid >> 4, pos = tid & 15;
    const int b0 = pos & 1;               // rows {b0, b0+2, b0+4, b0+6}
    const int c0 = (pos >> 1) << 2;       // cols c0..c0+3

    float acc[4][4];

    // ---- prologue: stage x_0 + phase-X partials (h-independent) ----
    #pragma unroll
    for (int l = 0; l < 2; ++l) {
        int q = tid + (l << 8);
        int b = q >> 6, k4 = (q & 63) << 2;
        *(float4*)&sXH[b][k4] =
            *(const float4*)(xin + ((size_t)(g8 + b) * NT + 0) * ND + k4);
    }
    __syncthreads();
    #pragma unroll
    for (int i = 0; i < 4; ++i)
        #pragma unroll
        for (int j = 0; j < 4; ++j) acc[i][j] = 0.f;
    #pragma unroll
    for (int u = 0; u < 4; ++u) STEP4(kk * 16 + 4 * u);

    for (int t = 0; t < NT; ++t) {
        const unsigned* hcur = hws + g * 4096 + (t & 1) * 2048;
        unsigned*       hnxt = hws + g * 4096 + ((t + 1) & 1) * 2048;

        // ---- A: spin until all 64 group flags >= t ----
        if (tid < GWG) {
            const unsigned* fp = &flags[(g * GWG + tid) * 32];
            while (gloadu_coh(fp) < (unsigned)t) {}
        }
        __syncthreads();

        // ---- B: coherent fp16 h_t (8 KB) -> unpack -> LDS ----
        {
            uint4 va = gload4u_coh(hcur + tid * 8);
            uint4 vb = gload4u_coh(hcur + tid * 8 + 4);
            asm volatile("s_waitcnt vmcnt(0)" ::: "memory");
            __builtin_amdgcn_sched_barrier(0);
            int b = tid >> 5, kcol = (tid & 31) << 4;   // 16 h floats per thread
            unsigned uu[8] = {va.x, va.y, va.z, va.w, vb.x, vb.y, vb.z, vb.w};
            float4* dst = (float4*)&sXH[b][ND + kcol];
            #pragma unroll
            for (int q = 0; q < 4; ++q) {
                __half2 h0 = *(__half2*)&uu[2 * q];
                __half2 h1 = *(__half2*)&uu[2 * q + 1];
                float2 f0 = __half22float2(h0), f1 = __half22float2(h1);
                dst[q] = make_float4(f0.x, f0.y, f1.x, f1.y);
            }
        }
        __syncthreads();

        // ---- C: phase-H accumulate (K=512) on top of phase-X partials ----
        #pragma unroll
        for (int u = 0; u < 8; ++u) STEP4(ND + kk * 32 + 4 * u);

        // ---- D: k-split partials ----
        #pragma unroll
        for (int i = 0; i < 4; ++i)
            *(float4*)&sZp[kk][b0 + 2 * i][c0] = *(float4*)&acc[i][0];
        __syncthreads();

        // ---- E: reduce 16 partials -> sZ ----
        {
            int b = tid >> 5, c = tid & 31;
            float z = sBias[c];
            #pragma unroll
            for (int k2 = 0; k2 < 16; ++k2) z += sZp[k2][b][c];
            sZ[b][c] = z;
        }
        __syncthreads();

        // ---- F (wave 0): gates + fp16-pack publish + flag ----
        if (tid < 64) {
            int b = tid >> 3, jj = tid & 7;
            float zi = sZ[b][jj];
            float zf = sZ[b][8 + jj];
            float zg = sZ[b][16 + jj];
            float zo = sZ[b][24 + jj];
            float cp = sC[b][jj];
            float cn = sigmoidf_(zf) * cp + sigmoidf_(zi) * tanhf(zg);
            sC[b][jj] = cn;
            float h  = sigmoidf_(zo) * tanhf(cn);
            float hp = __shfl_xor(h, 1, 64);
            if ((tid & 1) == 0) {
                __half2 pk;
                pk.x = __float2half(h);
                pk.y = __float2half(hp);
                gstoreu_coh(&hnxt[b * (NH / 2) + (j0 >> 1) + (jj >> 1)],
                            *(unsigned*)&pk);
            }
            asm volatile("s_waitcnt vmcnt(0)" ::: "memory");  // h at MALL first
            if (tid == 0)
                gstoreu_coh(&flags[(g * GWG + wgl) * 32], (unsigned)(t + 1));
        }

        // ---- G/H: overlap — stage x_{t+1} + phase-X partials ----
        if (t + 1 < NT) {
            #pragma unroll
            for (int l = 0; l < 2; ++l) {
                int q = tid + (l << 8);
                int b = q >> 6, k4 = (q & 63) << 2;
                *(float4*)&sXH[b][k4] =
                    *(const float4*)(xin + ((size_t)(g8 + b) * NT + (t + 1)) * ND + k4);
            }
            __syncthreads();
            #pragma unroll
            for (int i = 0; i < 4; ++i)
                #pragma unroll
                for (int j = 0; j < 4; ++j) acc[i][j] = 0.f;
            #pragma unroll
            for (int u = 0; u < 4; ++u) STEP4(kk * 16 + 4 * u);
        }
    }

    // ---- epilogue: wait group epoch NT, then out = h_last @ Wd + bd ----
    if (tid < GWG) {
        const unsigned* fp = &flags[(g * GWG + tid) * 32];
        while (gloadu_coh(fp) < (unsigned)NT) {}
    }
    __syncthreads();
    {
        const unsigned* hfin = hws + g * 4096;   // h_{2048} is in buf 0
        int b  = wgl >> 3;                       // local batch row
        int ob = (wgl & 7) << 5;                 // output col block
        float* sRow = &sZp[0][0][0];             // 512 f32, aliases sZp
        if (tid < 64) {
            uint4 v = gload4u_coh(hfin + b * (NH / 2) + tid * 4);
            asm volatile("s_waitcnt vmcnt(0)" ::: "memory");
            __builtin_amdgcn_sched_barrier(0);
            unsigned uu[4] = {v.x, v.y, v.z, v.w};
            #pragma unroll
            for (int q = 0; q < 4; ++q) {
                __half2 hq = *(__half2*)&uu[q];
                float2 f = __half22float2(hq);
                sRow[tid * 8 + 2 * q]     = f.x;
                sRow[tid * 8 + 2 * q + 1] = f.y;
            }
        }
        __syncthreads();
        int kd = tid >> 5, oo = tid & 31;
        float p = 0.f;
        for (int k = kd * 64; k < kd * 64 + 64; ++k)
            p = fmaf(sRow[k], Wd[k * NO + ob + oo], p);
        sRed[kd][oo] = p;
        __syncthreads();
        if (tid < 32) {
            float s = bd[ob + tid];
            #pragma unroll
            for (int k2 = 0; k2 < 8; ++k2) s += sRed[k2][tid];
            out[(g8 + b) * NO + ob + tid] = s;
        }
    }
}

extern "C" void kernel_launch(void* const* d_in, const int* in_sizes, int n_in,
                              void* d_out, int out_size, void* d_ws, size_t ws_size,
                              hipStream_t stream) {
    const float* xin = (const float*)d_in[0];
    const float* Wx  = (const float*)d_in[1];
    const float* Wh  = (const float*)d_in[2];
    const float* bz  = (const float*)d_in[3];
    const float* Wd  = (const float*)d_in[4];
    const float* bd  = (const float*)d_in[5];
    float* out = (float*)d_out;
    float* ws  = (float*)d_ws;

    void* args[] = { &xin, &Wx, &Wh, &bz, &Wd, &bd, &out, &ws };
    hipLaunchCooperativeKernel((const void*)lstm_fused, dim3(NWG), dim3(NTHR),
                               args, 0, stream);
}